// Round 1
// baseline (112.369 us; speedup 1.0000x reference)
//
#include <hip/hip_runtime.h>
#include <math.h>

// Problem constants (from reference): w=0.05, b=5.803, single species.
#define NBINS_MAX 512
constexpr float KW      = 0.05f;
constexpr float INV_KW  = 20.0f;           // 1/w
constexpr float CUT     = 8.0f * KW;       // truncate Gaussian at 8 sigma
constexpr float GNORM   = 0.3989422804014327f * INV_KW; // 1/(w*sqrt(2pi))
constexpr float COEFF   = 0.33674809f;     // b*b*0.01 = 5.803^2*0.01
constexpr float FOUR_PI = 12.566370614359172f;

// ---------------------------------------------------------------------------
// Kernel 1: pairwise min-image distances -> truncated-Gaussian KDE histogram.
// LDS per-block histogram, one global atomicAdd per bin per block at the end.
// ---------------------------------------------------------------------------
__global__ void __launch_bounds__(256)
pair_hist_kernel(const float* __restrict__ pos,
                 const float* __restrict__ cell,
                 const float* __restrict__ rbins,
                 float* __restrict__ gsum,
                 int N, int nbins)
{
    __shared__ float sh_hist[NBINS_MAX];
    __shared__ float sh_r[NBINS_MAX];
    const int t = threadIdx.x;
    for (int k = t; k < nbins; k += blockDim.x) {
        sh_hist[k] = 0.0f;
        sh_r[k]    = rbins[k];
    }

    // Load cell (row-major 3x3) and compute its inverse (uniform across wave).
    float cm[9];
#pragma unroll
    for (int k = 0; k < 9; ++k) cm[k] = cell[k];
    const float a00 = cm[0], a01 = cm[1], a02 = cm[2];
    const float a10 = cm[3], a11 = cm[4], a12 = cm[5];
    const float a20 = cm[6], a21 = cm[7], a22 = cm[8];
    const float det = a00*(a11*a22 - a12*a21)
                    - a01*(a10*a22 - a12*a20)
                    + a02*(a10*a21 - a11*a20);
    const float id = 1.0f / det;
    float im[9];
    im[0] = (a11*a22 - a12*a21)*id;  // inv[0][0]
    im[1] = (a02*a21 - a01*a22)*id;  // inv[0][1]
    im[2] = (a01*a12 - a02*a11)*id;  // inv[0][2]
    im[3] = (a12*a20 - a10*a22)*id;  // inv[1][0]
    im[4] = (a00*a22 - a02*a20)*id;  // inv[1][1]
    im[5] = (a02*a10 - a00*a12)*id;  // inv[1][2]
    im[6] = (a10*a21 - a11*a20)*id;  // inv[2][0]
    im[7] = (a01*a20 - a00*a21)*id;  // inv[2][1]
    im[8] = (a00*a11 - a01*a10)*id;  // inv[2][2]

    __syncthreads();

    const float r0     = sh_r[0];
    const float rend   = sh_r[nbins - 1];
    const float dr     = (rend - r0) / (float)(nbins - 1);
    const float inv_dr = 1.0f / dr;
    const float minb   = r0   - 3.0f * KW;   // window mask: excludes whole pairs
    const float maxb   = rend + 3.0f * KW;

    const long long total  = (long long)N * (long long)N;
    const long long stride = (long long)gridDim.x * blockDim.x;
    for (long long idx = (long long)blockIdx.x * blockDim.x + t; idx < total; idx += stride) {
        const int i = (int)(idx / N);
        const int j = (int)(idx - (long long)i * N);
        if (i >= j) continue;   // upper triangle only (matches triu_indices k=1)

        // diff = positions[j] - positions[i]
        const float dx = pos[3*j + 0] - pos[3*i + 0];
        const float dy = pos[3*j + 1] - pos[3*i + 1];
        const float dz = pos[3*j + 2] - pos[3*i + 2];
        // frac = diff (row vec) @ cell_inv
        float fx = dx*im[0] + dy*im[3] + dz*im[6];
        float fy = dx*im[1] + dy*im[4] + dz*im[7];
        float fz = dx*im[2] + dy*im[5] + dz*im[8];
        // minimum image: frac -= round(frac)  (rintf = round-half-even = jnp.round)
        fx -= rintf(fx); fy -= rintf(fy); fz -= rintf(fz);
        // mip = frac @ cell
        const float mx = fx*cm[0] + fy*cm[3] + fz*cm[6];
        const float my = fx*cm[1] + fy*cm[4] + fz*cm[7];
        const float mz = fx*cm[2] + fy*cm[5] + fz*cm[8];
        const float d  = sqrtf(mx*mx + my*my + mz*mz + 1e-10f);

        if (!(d > minb && d < maxb)) continue;

        // bins within +-8 sigma of d (r_bins are uniform linspace)
        int lo = (int)ceilf((d - CUT - r0) * inv_dr);
        int hi = (int)floorf((d + CUT - r0) * inv_dr);
        if (lo < 0) lo = 0;
        if (hi > nbins - 1) hi = nbins - 1;
        for (int k = lo; k <= hi; ++k) {
            const float tt = (sh_r[k] - d) * INV_KW;
            atomicAdd(&sh_hist[k], __expf(-0.5f * tt * tt) * GNORM);
        }
    }

    __syncthreads();
    for (int k = t; k < nbins; k += blockDim.x) {
        const float v = sh_hist[k];
        if (v != 0.0f) atomicAdd(&gsum[k], v);
    }
}

// ---------------------------------------------------------------------------
// Kernel 2: G(r), S(Q), F(Q). One block per Q value; 128 threads split the
// 400-point trapezoid integral. Block 0 additionally writes G(r).
// ---------------------------------------------------------------------------
__global__ void __launch_bounds__(128)
finalize_kernel(const float* __restrict__ gsum,
                const float* __restrict__ cell,
                const float* __restrict__ rbins,
                const float* __restrict__ qbins,
                float* __restrict__ out,
                int N, int nbins)
{
    const int qi = blockIdx.x;
    const int t  = threadIdx.x;
    __shared__ float red[128];

    // volume / density (uniform scalars)
    const float a00 = cell[0], a01 = cell[1], a02 = cell[2];
    const float a10 = cell[3], a11 = cell[4], a12 = cell[5];
    const float a20 = cell[6], a21 = cell[7], a22 = cell[8];
    const float det = a00*(a11*a22 - a12*a21)
                    - a01*(a10*a22 - a12*a20)
                    + a02*(a10*a21 - a11*a20);
    const float vol     = fabsf(det);
    const float n_pairs = 0.5f * (float)N * (float)(N - 1);
    const float rho     = (float)N / vol;
    const float pref    = vol / n_pairs;

    const float q    = qbins[qi];
    const float qinv = 1.0f / (q + 1e-10f);

    float acc = 0.0f;
    for (int k = t; k < nbins; k += blockDim.x) {
        const float r = rbins[k];
        const float g = pref * gsum[k] / (FOUR_PI * r * r);
        const float G = COEFF * (g - 1.0f);
        if (qi == 0) out[k] = G;   // block 0 covers all k -> writes G(r)
        // trapezoid weight for sample k
        const float w_lo = (k > 0)         ? (r - rbins[k - 1]) : 0.0f;
        const float w_hi = (k < nbins - 1) ? (rbins[k + 1] - r) : 0.0f;
        const float wgt  = 0.5f * (w_lo + w_hi);
        acc += wgt * r * G * sinf(q * r) * qinv;
    }

    red[t] = acc;
    __syncthreads();
    for (int s = blockDim.x >> 1; s > 0; s >>= 1) {
        if (t < s) red[t] += red[t + s];
        __syncthreads();
    }
    if (t == 0) {
        const float S = 1.0f + FOUR_PI * rho * red[0];
        out[nbins + qi]     = S;             // S(Q)
        out[2*nbins + qi]   = q * (S - 1.0f); // F(Q)
    }
}

// ---------------------------------------------------------------------------
extern "C" void kernel_launch(void* const* d_in, const int* in_sizes, int n_in,
                              void* d_out, int out_size, void* d_ws, size_t ws_size,
                              hipStream_t stream)
{
    const float* pos   = (const float*)d_in[0];  // (N,3) f32
    const float* cell  = (const float*)d_in[1];  // (3,3) f32
    const float* rbins = (const float*)d_in[2];  // (nbins,) f32
    const float* qbins = (const float*)d_in[3];  // (nbins,) f32
    float* out  = (float*)d_out;                 // (3, nbins) f32
    float* gsum = (float*)d_ws;                  // nbins f32 accumulator

    const int N     = in_sizes[0] / 3;
    const int nbins = in_sizes[2];

    hipMemsetAsync(gsum, 0, (size_t)nbins * sizeof(float), stream);

    const int threads = 256;
    long long total = (long long)N * (long long)N;
    int blocks = (int)((total + threads - 1) / threads);
    if (blocks > 512) blocks = 512;   // 2 blocks/CU; grid-stride covers the rest

    hipLaunchKernelGGL(pair_hist_kernel, dim3(blocks), dim3(threads), 0, stream,
                       pos, cell, rbins, gsum, N, nbins);
    hipLaunchKernelGGL(finalize_kernel, dim3(nbins), dim3(128), 0, stream,
                       gsum, cell, rbins, qbins, out, N, nbins);
}

// Round 2
// 95.737 us; speedup vs baseline: 1.1737x; 1.1737x over previous
//
#include <hip/hip_runtime.h>
#include <math.h>

// Problem constants (from reference): w=0.05, b=5.803, single species.
#define NBINS_MAX 512
constexpr float KW      = 0.05f;
constexpr float INV_KW  = 20.0f;           // 1/w
constexpr float CUT     = 8.0f * KW;       // truncate Gaussian at 8 sigma (omitted mass ~1e-12 in G)
constexpr float GNORM   = 0.3989422804014327f * INV_KW; // 1/(w*sqrt(2pi))
constexpr float COEFF   = 0.33674809f;     // b*b*0.01 = 5.803^2*0.01
constexpr float FOUR_PI = 12.566370614359172f;

// ---------------------------------------------------------------------------
// Kernel 1: pairwise min-image distances -> truncated-Gaussian KDE histogram.
// Block b handles rows (b, N-1-b): together exactly N-1 pairs -> perfect
// load balance, no divergent i>=j discard, no integer division.
// Inner KDE loop is pure VALU + fire-and-forget ds_add (r_k computed
// arithmetically; no LDS read -> no lgkmcnt stall in the loop).
// ---------------------------------------------------------------------------
__global__ void __launch_bounds__(512)
pair_hist_kernel(const float* __restrict__ pos,
                 const float* __restrict__ cell,
                 const float* __restrict__ rbins,
                 float* __restrict__ gsum,
                 int N, int nbins)
{
    __shared__ float sh_hist[NBINS_MAX];
    const int t = threadIdx.x;
    for (int k = t; k < nbins; k += blockDim.x) sh_hist[k] = 0.0f;

    // Load cell (row-major 3x3) and compute its inverse (uniform across wave).
    float cm[9];
#pragma unroll
    for (int k = 0; k < 9; ++k) cm[k] = cell[k];
    const float a00 = cm[0], a01 = cm[1], a02 = cm[2];
    const float a10 = cm[3], a11 = cm[4], a12 = cm[5];
    const float a20 = cm[6], a21 = cm[7], a22 = cm[8];
    const float det = a00*(a11*a22 - a12*a21)
                    - a01*(a10*a22 - a12*a20)
                    + a02*(a10*a21 - a11*a20);
    const float id = 1.0f / det;
    float im[9];
    im[0] = (a11*a22 - a12*a21)*id;
    im[1] = (a02*a21 - a01*a22)*id;
    im[2] = (a01*a12 - a02*a11)*id;
    im[3] = (a12*a20 - a10*a22)*id;
    im[4] = (a00*a22 - a02*a20)*id;
    im[5] = (a02*a10 - a00*a12)*id;
    im[6] = (a10*a21 - a11*a20)*id;
    im[7] = (a01*a20 - a00*a21)*id;
    im[8] = (a00*a11 - a01*a10)*id;

    const float r0     = rbins[0];
    const float rend   = rbins[nbins - 1];
    const float dr     = (rend - r0) / (float)(nbins - 1);
    const float inv_dr = 1.0f / dr;
    const float minb   = r0   - 3.0f * KW;   // window mask excludes whole pairs
    const float maxb   = rend + 3.0f * KW;
    const float ustep  = dr * INV_KW;

    __syncthreads();

    // Row pairing: A = b, B = N-1-b. cntA = N-1-A pairs (j>A), cntB = A pairs.
    const int A    = blockIdx.x;
    const int B    = N - 1 - A;
    const int cntA = N - 1 - A;
    const int cntB = (B != A) ? A : 0;   // guard for odd N center row
    const int tot  = cntA + cntB;

    const float Ax = pos[3*A+0], Ay = pos[3*A+1], Az = pos[3*A+2];
    const float Bx = pos[3*B+0], By = pos[3*B+1], Bz = pos[3*B+2];

    for (int p = t; p < tot; p += blockDim.x) {
        float ix, iy, iz; int j;
        if (p < cntA) { ix = Ax; iy = Ay; iz = Az; j = A + 1 + p; }
        else          { ix = Bx; iy = By; iz = Bz; j = B + 1 + (p - cntA); }

        const float dx = pos[3*j + 0] - ix;
        const float dy = pos[3*j + 1] - iy;
        const float dz = pos[3*j + 2] - iz;
        // frac = diff @ cell_inv
        float fx = dx*im[0] + dy*im[3] + dz*im[6];
        float fy = dx*im[1] + dy*im[4] + dz*im[7];
        float fz = dx*im[2] + dy*im[5] + dz*im[8];
        // minimum image (rintf = round-half-even = jnp.round)
        fx -= rintf(fx); fy -= rintf(fy); fz -= rintf(fz);
        // mip = frac @ cell
        const float mx = fx*cm[0] + fy*cm[3] + fz*cm[6];
        const float my = fx*cm[1] + fy*cm[4] + fz*cm[7];
        const float mz = fx*cm[2] + fy*cm[5] + fz*cm[8];
        const float d  = sqrtf(mx*mx + my*my + mz*mz + 1e-10f);

        if (!(d > minb && d < maxb)) continue;

        int lo = (int)ceilf ((d - CUT - r0) * inv_dr);
        int hi = (int)floorf((d + CUT - r0) * inv_dr);
        if (lo < 0) lo = 0;
        if (hi > nbins - 1) hi = nbins - 1;

        // u_k = (r_k - d)/w advanced incrementally; body has no memory waits.
        float u = (r0 + (float)lo * dr - d) * INV_KW;
        for (int k = lo; k <= hi; ++k) {
            atomicAdd(&sh_hist[k], __expf(-0.5f * u * u) * GNORM);
            u += ustep;
        }
    }

    __syncthreads();
    for (int k = t; k < nbins; k += blockDim.x) {
        const float v = sh_hist[k];
        if (v != 0.0f) atomicAdd(&gsum[k], v);
    }
}

// ---------------------------------------------------------------------------
// Kernel 2: G(r), S(Q), F(Q). One 64-lane wave per Q; shuffle reduction.
// Block 0 additionally writes G(r).
// ---------------------------------------------------------------------------
__global__ void __launch_bounds__(64)
finalize_kernel(const float* __restrict__ gsum,
                const float* __restrict__ cell,
                const float* __restrict__ rbins,
                const float* __restrict__ qbins,
                float* __restrict__ out,
                int N, int nbins)
{
    const int qi = blockIdx.x;
    const int t  = threadIdx.x;

    const float a00 = cell[0], a01 = cell[1], a02 = cell[2];
    const float a10 = cell[3], a11 = cell[4], a12 = cell[5];
    const float a20 = cell[6], a21 = cell[7], a22 = cell[8];
    const float det = a00*(a11*a22 - a12*a21)
                    - a01*(a10*a22 - a12*a20)
                    + a02*(a10*a21 - a11*a20);
    const float vol     = fabsf(det);
    const float n_pairs = 0.5f * (float)N * (float)(N - 1);
    const float rho     = (float)N / vol;
    const float pref    = vol / n_pairs;

    const float q    = qbins[qi];
    const float qinv = 1.0f / (q + 1e-10f);

    float acc = 0.0f;
    for (int k = t; k < nbins; k += 64) {
        const float r = rbins[k];
        const float g = pref * gsum[k] / (FOUR_PI * r * r);
        const float G = COEFF * (g - 1.0f);
        if (qi == 0) out[k] = G;   // block 0's lanes cover all k
        const float w_lo = (k > 0)         ? (r - rbins[k - 1]) : 0.0f;
        const float w_hi = (k < nbins - 1) ? (rbins[k + 1] - r) : 0.0f;
        acc += 0.5f * (w_lo + w_hi) * r * G * __sinf(q * r) * qinv;
    }

    // wave-64 shuffle reduction
#pragma unroll
    for (int off = 32; off > 0; off >>= 1)
        acc += __shfl_down(acc, off, 64);

    if (t == 0) {
        const float S = 1.0f + FOUR_PI * rho * acc;
        out[nbins + qi]   = S;               // S(Q)
        out[2*nbins + qi] = q * (S - 1.0f);  // F(Q)
    }
}

// ---------------------------------------------------------------------------
extern "C" void kernel_launch(void* const* d_in, const int* in_sizes, int n_in,
                              void* d_out, int out_size, void* d_ws, size_t ws_size,
                              hipStream_t stream)
{
    const float* pos   = (const float*)d_in[0];  // (N,3) f32
    const float* cell  = (const float*)d_in[1];  // (3,3) f32
    const float* rbins = (const float*)d_in[2];  // (nbins,) f32
    const float* qbins = (const float*)d_in[3];  // (nbins,) f32
    float* out  = (float*)d_out;                 // (3, nbins) f32
    float* gsum = (float*)d_ws;                  // nbins f32 accumulator

    const int N     = in_sizes[0] / 3;
    const int nbins = in_sizes[2];

    hipMemsetAsync(gsum, 0, (size_t)nbins * sizeof(float), stream);

    const int blocks = (N + 1) / 2;   // row-pair mapping: each block = N-1 pairs
    hipLaunchKernelGGL(pair_hist_kernel, dim3(blocks), dim3(512), 0, stream,
                       pos, cell, rbins, gsum, N, nbins);
    hipLaunchKernelGGL(finalize_kernel, dim3(nbins), dim3(64), 0, stream,
                       gsum, cell, rbins, qbins, out, N, nbins);
}

// Round 3
// 94.933 us; speedup vs baseline: 1.1837x; 1.0085x over previous
//
#include <hip/hip_runtime.h>
#include <math.h>

// Problem constants (from reference): w=0.05, b=5.803, single species.
#define NBINS_MAX 512
constexpr float KW      = 0.05f;
constexpr float INV_KW  = 20.0f;           // 1/w
constexpr float CUT     = 8.0f * KW;       // truncate Gaussian at 8 sigma (omitted mass ~1e-12 in G)
constexpr float GNORM   = 0.3989422804014327f * INV_KW; // 1/(w*sqrt(2pi))
constexpr float COEFF   = 0.33674809f;     // b*b*0.01 = 5.803^2*0.01
constexpr float FOUR_PI = 12.566370614359172f;

// ---------------------------------------------------------------------------
// Kernel 1: pairwise min-image distances -> truncated-Gaussian KDE into an
// LDS histogram (native ds_add_f32 via unsafeAtomicAdd — default atomicAdd on
// fp32 is gated to a CAS loop). Flush = plain coalesced stores of a per-block
// partial histogram into d_ws. NO global atomics (R1/R2 showed the 205k
// device-scope fp atomics were a ~40 us serialized chain: WRITE_SIZE 714 KB
// for a 1.6 KB logical output).
// Block b handles rows (b, N-1-b): exactly N-1 pairs -> perfect balance.
// ---------------------------------------------------------------------------
__global__ void __launch_bounds__(512)
pair_hist_kernel(const float* __restrict__ pos,
                 const float* __restrict__ cell,
                 const float* __restrict__ rbins,
                 float* __restrict__ partial,   // [gridDim.x][nbins]
                 int N, int nbins)
{
    __shared__ float sh_hist[NBINS_MAX];
    const int t = threadIdx.x;
    for (int k = t; k < nbins; k += blockDim.x) sh_hist[k] = 0.0f;

    // Load cell (row-major 3x3) and compute its inverse (uniform across wave).
    float cm[9];
#pragma unroll
    for (int k = 0; k < 9; ++k) cm[k] = cell[k];
    const float a00 = cm[0], a01 = cm[1], a02 = cm[2];
    const float a10 = cm[3], a11 = cm[4], a12 = cm[5];
    const float a20 = cm[6], a21 = cm[7], a22 = cm[8];
    const float det = a00*(a11*a22 - a12*a21)
                    - a01*(a10*a22 - a12*a20)
                    + a02*(a10*a21 - a11*a20);
    const float id = 1.0f / det;
    float im[9];
    im[0] = (a11*a22 - a12*a21)*id;
    im[1] = (a02*a21 - a01*a22)*id;
    im[2] = (a01*a12 - a02*a11)*id;
    im[3] = (a12*a20 - a10*a22)*id;
    im[4] = (a00*a22 - a02*a20)*id;
    im[5] = (a02*a10 - a00*a12)*id;
    im[6] = (a10*a21 - a11*a20)*id;
    im[7] = (a01*a20 - a00*a21)*id;
    im[8] = (a00*a11 - a01*a10)*id;

    const float r0     = rbins[0];
    const float rend   = rbins[nbins - 1];
    const float dr     = (rend - r0) / (float)(nbins - 1);
    const float inv_dr = 1.0f / dr;
    const float minb   = r0   - 3.0f * KW;   // window mask excludes whole pairs
    const float maxb   = rend + 3.0f * KW;
    const float ustep  = dr * INV_KW;

    __syncthreads();

    // Row pairing: A = b, B = N-1-b. cntA = N-1-A pairs (j>A), cntB = A pairs.
    const int A    = blockIdx.x;
    const int B    = N - 1 - A;
    const int cntA = N - 1 - A;
    const int cntB = (B != A) ? A : 0;   // guard for odd N center row
    const int tot  = cntA + cntB;

    const float Ax = pos[3*A+0], Ay = pos[3*A+1], Az = pos[3*A+2];
    const float Bx = pos[3*B+0], By = pos[3*B+1], Bz = pos[3*B+2];

    for (int p = t; p < tot; p += blockDim.x) {
        float ix, iy, iz; int j;
        if (p < cntA) { ix = Ax; iy = Ay; iz = Az; j = A + 1 + p; }
        else          { ix = Bx; iy = By; iz = Bz; j = B + 1 + (p - cntA); }

        const float dx = pos[3*j + 0] - ix;
        const float dy = pos[3*j + 1] - iy;
        const float dz = pos[3*j + 2] - iz;
        // frac = diff @ cell_inv
        float fx = dx*im[0] + dy*im[3] + dz*im[6];
        float fy = dx*im[1] + dy*im[4] + dz*im[7];
        float fz = dx*im[2] + dy*im[5] + dz*im[8];
        // minimum image (rintf = round-half-even = jnp.round)
        fx -= rintf(fx); fy -= rintf(fy); fz -= rintf(fz);
        // mip = frac @ cell
        const float mx = fx*cm[0] + fy*cm[3] + fz*cm[6];
        const float my = fx*cm[1] + fy*cm[4] + fz*cm[7];
        const float mz = fx*cm[2] + fy*cm[5] + fz*cm[8];
        const float d  = sqrtf(mx*mx + my*my + mz*mz + 1e-10f);

        if (!(d > minb && d < maxb)) continue;

        int lo = (int)ceilf ((d - CUT - r0) * inv_dr);
        int hi = (int)floorf((d + CUT - r0) * inv_dr);
        if (lo < 0) lo = 0;
        if (hi > nbins - 1) hi = nbins - 1;

        // u_k = (r_k - d)/w advanced incrementally; body: mul,mul,exp,mul,ds_add.
        float u = (r0 + (float)lo * dr - d) * INV_KW;
        for (int k = lo; k <= hi; ++k) {
            unsafeAtomicAdd(&sh_hist[k], __expf(-0.5f * u * u) * GNORM);
            u += ustep;
        }
    }

    __syncthreads();
    // Coalesced plain stores of the per-block partial (write ALL bins:
    // d_ws is poisoned before every launch).
    float* myrow = partial + (size_t)blockIdx.x * nbins;
    for (int k = t; k < nbins; k += blockDim.x) myrow[k] = sh_hist[k];
}

// ---------------------------------------------------------------------------
// Kernel 2: reduce per-block partials -> gsum.  Block k sums column k over
// npart rows (strided loads, L2/L3-hot), shuffle reduction.
// ---------------------------------------------------------------------------
__global__ void __launch_bounds__(64)
reduce_kernel(const float* __restrict__ partial,
              float* __restrict__ gsum,
              int npart, int nbins)
{
    const int k = blockIdx.x;
    const int t = threadIdx.x;
    float acc = 0.0f;
    for (int p = t; p < npart; p += 64)
        acc += partial[(size_t)p * nbins + k];
#pragma unroll
    for (int off = 32; off > 0; off >>= 1)
        acc += __shfl_down(acc, off, 64);
    if (t == 0) gsum[k] = acc;
}

// ---------------------------------------------------------------------------
// Kernel 3: G(r), S(Q), F(Q). One 64-lane wave per Q; shuffle reduction.
// Block 0 additionally writes G(r).
// ---------------------------------------------------------------------------
__global__ void __launch_bounds__(64)
finalize_kernel(const float* __restrict__ gsum,
                const float* __restrict__ cell,
                const float* __restrict__ rbins,
                const float* __restrict__ qbins,
                float* __restrict__ out,
                int N, int nbins)
{
    const int qi = blockIdx.x;
    const int t  = threadIdx.x;

    const float a00 = cell[0], a01 = cell[1], a02 = cell[2];
    const float a10 = cell[3], a11 = cell[4], a12 = cell[5];
    const float a20 = cell[6], a21 = cell[7], a22 = cell[8];
    const float det = a00*(a11*a22 - a12*a21)
                    - a01*(a10*a22 - a12*a20)
                    + a02*(a10*a21 - a11*a20);
    const float vol     = fabsf(det);
    const float n_pairs = 0.5f * (float)N * (float)(N - 1);
    const float rho     = (float)N / vol;
    const float pref    = vol / n_pairs;

    const float q    = qbins[qi];
    const float qinv = 1.0f / (q + 1e-10f);

    float acc = 0.0f;
    for (int k = t; k < nbins; k += 64) {
        const float r = rbins[k];
        const float g = pref * gsum[k] / (FOUR_PI * r * r);
        const float G = COEFF * (g - 1.0f);
        if (qi == 0) out[k] = G;   // block 0's lanes cover all k
        const float w_lo = (k > 0)         ? (r - rbins[k - 1]) : 0.0f;
        const float w_hi = (k < nbins - 1) ? (rbins[k + 1] - r) : 0.0f;
        acc += 0.5f * (w_lo + w_hi) * r * G * __sinf(q * r) * qinv;
    }

#pragma unroll
    for (int off = 32; off > 0; off >>= 1)
        acc += __shfl_down(acc, off, 64);

    if (t == 0) {
        const float S = 1.0f + FOUR_PI * rho * acc;
        out[nbins + qi]   = S;               // S(Q)
        out[2*nbins + qi] = q * (S - 1.0f);  // F(Q)
    }
}

// ---------------------------------------------------------------------------
extern "C" void kernel_launch(void* const* d_in, const int* in_sizes, int n_in,
                              void* d_out, int out_size, void* d_ws, size_t ws_size,
                              hipStream_t stream)
{
    const float* pos   = (const float*)d_in[0];  // (N,3) f32
    const float* cell  = (const float*)d_in[1];  // (3,3) f32
    const float* rbins = (const float*)d_in[2];  // (nbins,) f32
    const float* qbins = (const float*)d_in[3];  // (nbins,) f32
    float* out = (float*)d_out;                  // (3, nbins) f32

    const int N     = in_sizes[0] / 3;
    const int nbins = in_sizes[2];
    const int npart = (N + 1) / 2;               // pair-kernel block count

    float* partial = (float*)d_ws;               // [npart][nbins]
    float* gsum    = partial + (size_t)npart * nbins;  // [nbins]

    hipLaunchKernelGGL(pair_hist_kernel, dim3(npart), dim3(512), 0, stream,
                       pos, cell, rbins, partial, N, nbins);
    hipLaunchKernelGGL(reduce_kernel, dim3(nbins), dim3(64), 0, stream,
                       partial, gsum, npart, nbins);
    hipLaunchKernelGGL(finalize_kernel, dim3(nbins), dim3(64), 0, stream,
                       gsum, cell, rbins, qbins, out, N, nbins);
}